// Round 2
// baseline (519.121 us; speedup 1.0000x reference)
//
#include <hip/hip_runtime.h>
#include <math.h>
#include <float.h>
#include <limits.h>

#define BN      32768   // B*N query rows
#define D_IN    1024
#define E_DIM   128
#define CB_N    8192

typedef _Float16 f16x8 __attribute__((ext_vector_type(8)));
typedef _Float16 f16x4 __attribute__((ext_vector_type(4)));
typedef float    f32x4 __attribute__((ext_vector_type(4)));

// Workspace:
//   ph  : [CB_N/16][4][64][8] f16   2 MB  (ncb*256 hi, B-frag packed)
//   pl  : same                      2 MB
//   rph : [32*8][64][8] f16         0.25 MB (rp*64 hi, B-frag packed)
//   rpl : same                      0.25 MB

// ---------------------------------------------------------------------------
// Kernel 1 (fused packs): blocks [0,512) pack codebook, blocks [512,544)
// pack rp via LDS-staged coalesced loads. (validated r1)
// ---------------------------------------------------------------------------
__global__ __launch_bounds__(256) void pack_all_kernel(
    const float* __restrict__ cb, _Float16* __restrict__ ph,
    _Float16* __restrict__ pl,
    const float* __restrict__ rp, _Float16* __restrict__ rph,
    _Float16* __restrict__ rpl) {
    __shared__ float L[16][129];
    __shared__ float R[32][132];
    const int t = threadIdx.x;
    const int b = blockIdx.x;

    if (b < 512) {
        const int g = b;
        const int c = t >> 4, p = t & 15;
        const float4 v0 = *(const float4*)&cb[(size_t)(g * 16 + c) * E_DIM + p * 8];
        const float4 v1 = *(const float4*)&cb[(size_t)(g * 16 + c) * E_DIM + p * 8 + 4];
        float ss = v0.x * v0.x + v0.y * v0.y + v0.z * v0.z + v0.w * v0.w
                 + v1.x * v1.x + v1.y * v1.y + v1.z * v1.z + v1.w * v1.w;
#pragma unroll
        for (int m = 1; m < 16; m <<= 1) ss += __shfl_xor(ss, m);
        const float inv = 256.0f / fmaxf(sqrtf(ss), 1e-12f);

        L[c][p * 8 + 0] = v0.x * inv; L[c][p * 8 + 1] = v0.y * inv;
        L[c][p * 8 + 2] = v0.z * inv; L[c][p * 8 + 3] = v0.w * inv;
        L[c][p * 8 + 4] = v1.x * inv; L[c][p * 8 + 5] = v1.y * inv;
        L[c][p * 8 + 6] = v1.z * inv; L[c][p * 8 + 7] = v1.w * inv;
        __syncthreads();

        const int kb = t >> 6, lane = t & 63;
        const int quad = (lane >> 4), col = lane & 15;
        f16x8 h, l;
#pragma unroll
        for (int j = 0; j < 8; ++j) {
            const float v = L[col][kb * 32 + quad * 8 + j];
            const _Float16 hv = (_Float16)v;
            h[j] = hv;
            l[j] = (_Float16)(v - (float)hv);
        }
        const size_t off = ((size_t)(g * 4 + kb) * 64 + lane) * 8;
        *(f16x8*)&ph[off] = h;
        *(f16x8*)&pl[off] = l;
    } else {
        const int kb = b - 512;
        const int r = t >> 3, c0 = (t & 7) * 16;
#pragma unroll
        for (int i = 0; i < 4; ++i)
            *(float4*)&R[r][c0 + i * 4] =
                *(const float4*)&rp[(size_t)(kb * 32 + r) * E_DIM + c0 + i * 4];
        __syncthreads();

        const int w = t >> 6, lane = t & 63;
        const int quad = lane >> 4, col = lane & 15;
#pragma unroll
        for (int h2 = 0; h2 < 2; ++h2) {
            const int nt = w * 2 + h2;
            f16x8 hh, ll;
#pragma unroll
            for (int j = 0; j < 8; ++j) {
                const float v = R[quad * 8 + j][nt * 16 + col] * 64.0f;
                const _Float16 hv = (_Float16)v;
                hh[j] = hv;
                ll[j] = (_Float16)(v - (float)hv);
            }
            const size_t off = ((size_t)((kb * 8 + nt) * 64) + lane) * 8;
            *(f16x8*)&rph[off] = hh;
            *(f16x8*)&rpl[off] = ll;
        }
    }
}

// ---------------------------------------------------------------------------
// Kernel 2: FUSED proj + scores + argmax. Qtile = 128, 512 threads, 8 waves.
// Phase 1: barrier-free direct-from-global proj (r1 structure); wave w:
//   wq1 = w>>2 (query 64-half), wn = w&3 (e-tile pair). P[128][128] -> LDS.
// Phase 2: wave w: wq = w>>1 (query quarter, 32 q), wc = w&1 (code half).
//   Codebook frags staged L2->LDS once per block in 32-code double-buffered
//   chunks (reg-staged, T14 issue-early/write-late). The P buffer is dead
//   after A-frag extraction, so the staging buffer aliases it.
//   L2->CU codebook traffic: 16.8 MB -> 4 MB per CU.
// ---------------------------------------------------------------------------
#define PPITCH  132                  // proj buffer row pitch (dwords)
#define P_BYTES  (128 * PPITCH * 4)  // 67,584 B
#define BST_HALF 16384               // per code-half chunk bytes (hi+lo, 32 codes)
#define BST_BUF  32768               // both halves
#define NCHUNK   128                 // 4096 codes / 32 per half

__global__ __launch_bounds__(512) void fused_kernel(
    const float* __restrict__ x,
    const _Float16* __restrict__ rph, const _Float16* __restrict__ rpl,
    const _Float16* __restrict__ ph, const _Float16* __restrict__ pl,
    int* __restrict__ out) {
    __shared__ __align__(16) char SMEM[P_BYTES];   // P (phase 1/2 handoff) | Bst[2] (phase 2)
    __shared__ float ls[8][32];
    __shared__ int   li[8][32];

    const int tid  = threadIdx.x;
    const int lane = tid & 63;
    const int w    = tid >> 6;
    const int quad = lane >> 4, col = lane & 15;
    const int qb   = blockIdx.x * 128;

    float* Pf = (float*)SMEM;
    char*  Bst = SMEM;

    // ======================= Phase 1: projection (LDS-free) =================
    const int wn  = w & 3;      // e-tile pair: nt = wn*2 + h
    const int wq1 = w >> 2;     // query 64-half
    const int qbw = qb + wq1 * 64;

    const float* xr[4];
#pragma unroll
    for (int mt = 0; mt < 4; ++mt)
        xr[mt] = x + (size_t)(qbw + mt * 16 + col) * D_IN + quad * 8;

    f32x4 acc[4][2];
#pragma unroll
    for (int mt = 0; mt < 4; ++mt)
#pragma unroll
        for (int h = 0; h < 2; ++h) acc[mt][h] = (f32x4){0.f, 0.f, 0.f, 0.f};

    float4 pA[4][2];
#pragma unroll
    for (int mt = 0; mt < 4; ++mt) {
        pA[mt][0] = *(const float4*)(xr[mt] + 0);
        pA[mt][1] = *(const float4*)(xr[mt] + 4);
    }
    f16x8 bhc[2], blc[2];
#pragma unroll
    for (int h = 0; h < 2; ++h) {
        const size_t off = ((size_t)(wn * 2 + h) * 64 + lane) * 8;
        bhc[h] = *(const f16x8*)&rph[off];
        blc[h] = *(const f16x8*)&rpl[off];
    }

    for (int kb = 0; kb < 32; ++kb) {
        f16x8 ah1[4], al1[4];
#pragma unroll
        for (int mt = 0; mt < 4; ++mt) {
            const float vv[8] = {pA[mt][0].x, pA[mt][0].y, pA[mt][0].z, pA[mt][0].w,
                                 pA[mt][1].x, pA[mt][1].y, pA[mt][1].z, pA[mt][1].w};
            f16x8 hh, ll;
#pragma unroll
            for (int j = 0; j < 8; ++j) {
                const float v = vv[j] * 512.0f;
                const _Float16 hv = (_Float16)v;
                hh[j] = hv;
                ll[j] = (_Float16)(v - (float)hv);
            }
            ah1[mt] = hh;
            al1[mt] = ll;
        }

        if (kb + 1 < 32) {
#pragma unroll
            for (int mt = 0; mt < 4; ++mt) {
                pA[mt][0] = *(const float4*)(xr[mt] + (kb + 1) * 32);
                pA[mt][1] = *(const float4*)(xr[mt] + (kb + 1) * 32 + 4);
            }
        }

        f16x8 bh1[2] = {bhc[0], bhc[1]};
        f16x8 bl1[2] = {blc[0], blc[1]};
        if (kb + 1 < 32) {
#pragma unroll
            for (int h = 0; h < 2; ++h) {
                const size_t off = ((size_t)((kb + 1) * 8 + wn * 2 + h) * 64 + lane) * 8;
                bhc[h] = *(const f16x8*)&rph[off];
                blc[h] = *(const f16x8*)&rpl[off];
            }
        }

#pragma unroll
        for (int mt = 0; mt < 4; ++mt)
#pragma unroll
            for (int h = 0; h < 2; ++h)
                acc[mt][h] = __builtin_amdgcn_mfma_f32_16x16x32_f16(ah1[mt], bh1[h], acc[mt][h], 0, 0, 0);
#pragma unroll
        for (int mt = 0; mt < 4; ++mt)
#pragma unroll
            for (int h = 0; h < 2; ++h)
                acc[mt][h] = __builtin_amdgcn_mfma_f32_16x16x32_f16(ah1[mt], bl1[h], acc[mt][h], 0, 0, 0);
#pragma unroll
        for (int mt = 0; mt < 4; ++mt)
#pragma unroll
            for (int h = 0; h < 2; ++h)
                acc[mt][h] = __builtin_amdgcn_mfma_f32_16x16x32_f16(al1[mt], bh1[h], acc[mt][h], 0, 0, 0);
    }

    // Write proj*16 (f32) to LDS. C/D: row = mt*16 + quad*4 + r, col(e) = h*16 + lane&15.
#pragma unroll
    for (int mt = 0; mt < 4; ++mt)
#pragma unroll
        for (int h = 0; h < 2; ++h)
#pragma unroll
            for (int r = 0; r < 4; ++r) {
                const int row = wq1 * 64 + mt * 16 + quad * 4 + r;
                const int cc  = wn * 32 + h * 16 + col;
                Pf[row * PPITCH + cc] = acc[mt][h][r] * (1.0f / 2048.0f);
            }
    __syncthreads();

    // ======================= Phase 2: scores + argmax =======================
    const int wq = w >> 1;   // query quarter: m-tiles wq*2, wq*2+1
    const int wc = w & 1;    // code half: [wc*4096, wc*4096+4096)

    // A frags from P: A[m=col][k=quad*8+j], split hi/lo.
    f16x8 ah[2][4], al[2][4];
#pragma unroll
    for (int mt2 = 0; mt2 < 2; ++mt2)
#pragma unroll
        for (int kb = 0; kb < 4; ++kb) {
            const int base = (wq * 32 + mt2 * 16 + col) * PPITCH + kb * 32 + quad * 8;
            const float4 v0 = *(const float4*)&Pf[base];
            const float4 v1 = *(const float4*)&Pf[base + 4];
            const float vv[8] = {v0.x, v0.y, v0.z, v0.w, v1.x, v1.y, v1.z, v1.w};
            f16x8 hh, ll;
#pragma unroll
            for (int j = 0; j < 8; ++j) {
                const _Float16 hv = (_Float16)vv[j];
                hh[j] = hv;
                ll[j] = (_Float16)(vv[j] - (float)hv);
            }
            ah[mt2][kb] = hh;
            al[mt2][kb] = ll;
        }
    __syncthreads();   // everyone done with P; Bst may now overwrite it

    // Staging role: region r_ = w>>1 -> (code half h2_, hi/lo sel_); wh_ = 4KB sub.
    const int r_   = w >> 1;
    const int h2_  = r_ >> 1, sel_ = r_ & 1;
    const int wh_  = w & 1;
    const char* sbase   = (const char*)(sel_ ? pl : ph);
    const size_t goff   = (size_t)h2_ * 1048576 + (size_t)wh_ * 4096 + (size_t)lane * 16;
    const int    loff   = h2_ * BST_HALF + sel_ * 8192 + wh_ * 4096 + lane * 16;

    float4 stg[4];
    // prologue: stage chunk 0 into buf 0
#pragma unroll
    for (int i = 0; i < 4; ++i)
        stg[i] = *(const float4*)(sbase + goff + i * 1024);
#pragma unroll
    for (int i = 0; i < 4; ++i)
        *(float4*)(Bst + loff + i * 1024) = stg[i];
    __syncthreads();

    float bs[8];
    int   bi[8];
#pragma unroll
    for (int s = 0; s < 8; ++s) { bs[s] = -FLT_MAX; bi[s] = 0; }

    for (int c = 0; c < NCHUNK; ++c) {
        const int cur = c & 1;
        // issue next-chunk loads early (latency hides under the 48 MFMAs)
        if (c + 1 < NCHUNK) {
#pragma unroll
            for (int i = 0; i < 4; ++i)
                stg[i] = *(const float4*)(sbase + goff + (size_t)(c + 1) * 8192 + i * 1024);
        }

        const char* bbase = Bst + cur * BST_BUF + wc * BST_HALF;
#pragma unroll
        for (int tt = 0; tt < 2; ++tt) {
            f16x8 bh2[4], bl2[4];
#pragma unroll
            for (int kb = 0; kb < 4; ++kb) {
                bh2[kb] = *(const f16x8*)(bbase + (tt * 4 + kb) * 1024 + lane * 16);
                bl2[kb] = *(const f16x8*)(bbase + 8192 + (tt * 4 + kb) * 1024 + lane * 16);
            }

            f32x4 sacc[2];
#pragma unroll
            for (int mt2 = 0; mt2 < 2; ++mt2) sacc[mt2] = (f32x4){0.f, 0.f, 0.f, 0.f};

            __builtin_amdgcn_s_setprio(1);
#pragma unroll
            for (int kb = 0; kb < 4; ++kb)
#pragma unroll
                for (int mt2 = 0; mt2 < 2; ++mt2)
                    sacc[mt2] = __builtin_amdgcn_mfma_f32_16x16x32_f16(ah[mt2][kb], bh2[kb], sacc[mt2], 0, 0, 0);
#pragma unroll
            for (int kb = 0; kb < 4; ++kb)
#pragma unroll
                for (int mt2 = 0; mt2 < 2; ++mt2)
                    sacc[mt2] = __builtin_amdgcn_mfma_f32_16x16x32_f16(ah[mt2][kb], bl2[kb], sacc[mt2], 0, 0, 0);
#pragma unroll
            for (int kb = 0; kb < 4; ++kb)
#pragma unroll
                for (int mt2 = 0; mt2 < 2; ++mt2)
                    sacc[mt2] = __builtin_amdgcn_mfma_f32_16x16x32_f16(al[mt2][kb], bh2[kb], sacc[mt2], 0, 0, 0);
            __builtin_amdgcn_s_setprio(0);

            const int code = wc * 4096 + (c * 2 + tt) * 16 + col;
#pragma unroll
            for (int mt2 = 0; mt2 < 2; ++mt2)
#pragma unroll
                for (int r = 0; r < 4; ++r) {
                    const float v = sacc[mt2][r];
                    const int s = mt2 * 4 + r;
                    if (v > bs[s]) { bs[s] = v; bi[s] = code; }  // ascending: > keeps min idx
                }
        }

        // write-late into the other buffer, then one barrier per chunk
        if (c + 1 < NCHUNK) {
            const int nxt = (c + 1) & 1;
#pragma unroll
            for (int i = 0; i < 4; ++i)
                *(float4*)(Bst + nxt * BST_BUF + loff + i * 1024) = stg[i];
            __syncthreads();
        }
    }

    // Reduce the 16 code-columns per query (lanes differ in low 4 bits).
#pragma unroll
    for (int s = 0; s < 8; ++s) {
#pragma unroll
        for (int m = 1; m < 16; m <<= 1) {
            const float os = __shfl_xor(bs[s], m);
            const int   oi = __shfl_xor(bi[s], m);
            if (os > bs[s] || (os == bs[s] && oi < bi[s])) { bs[s] = os; bi[s] = oi; }
        }
    }

    if (col == 0) {
#pragma unroll
        for (int mt2 = 0; mt2 < 2; ++mt2)
#pragma unroll
            for (int r = 0; r < 4; ++r) {
                ls[w][mt2 * 16 + quad * 4 + r] = bs[mt2 * 4 + r];
                li[w][mt2 * 16 + quad * 4 + r] = bi[mt2 * 4 + r];
            }
    }
    __syncthreads();

    // Merge the two code halves (wc=0 codes < wc=1 codes: strict > keeps min idx).
    if (tid < 128) {
        const int q   = tid;
        const int wqf = q >> 5;
        const int q32 = q & 31;
        float s = ls[wqf * 2 + 0][q32];
        int   i = li[wqf * 2 + 0][q32];
        const float os = ls[wqf * 2 + 1][q32];
        if (os > s) { s = os; i = li[wqf * 2 + 1][q32]; }
        out[qb + q] = i;
    }
}

// ---------------------------------------------------------------------------
extern "C" void kernel_launch(void* const* d_in, const int* in_sizes, int n_in,
                              void* d_out, int out_size, void* d_ws, size_t ws_size,
                              hipStream_t stream) {
    const float* x  = (const float*)d_in[0];   // [8,4096,1024]
    const float* rp = (const float*)d_in[1];   // [1024,128]
    const float* cb = (const float*)d_in[2];   // [8192,128]
    int* out = (int*)d_out;                    // [8,4096] int32

    _Float16* ph  = (_Float16*)d_ws;                         // 2 MB
    _Float16* pl  = ph  + (size_t)CB_N * E_DIM;              // 2 MB
    _Float16* rph = pl  + (size_t)CB_N * E_DIM;              // 256 KB
    _Float16* rpl = rph + (size_t)D_IN * E_DIM;              // 256 KB

    pack_all_kernel<<<CB_N / 16 + 32, 256, 0, stream>>>(cb, ph, pl, rp, rph, rpl);
    fused_kernel<<<BN / 128, 512, 0, stream>>>(x, rph, rpl, ph, pl, out);
}

// Round 3
// 407.306 us; speedup vs baseline: 1.2745x; 1.2745x over previous
//
#include <hip/hip_runtime.h>
#include <math.h>
#include <float.h>
#include <limits.h>

#define BN      32768   // B*N query rows
#define D_IN    1024
#define E_DIM   128
#define CB_N    8192

typedef _Float16 f16x8 __attribute__((ext_vector_type(8)));
typedef _Float16 f16x4 __attribute__((ext_vector_type(4)));
typedef float    f32x4 __attribute__((ext_vector_type(4)));

// async global->LDS, 16 B per lane. LDS dest = wave-uniform base + lane*16.
#define GLL16(gsrc, ldst)                                                      \
    __builtin_amdgcn_global_load_lds(                                          \
        (const __attribute__((address_space(1))) unsigned int*)(const void*)(gsrc), \
        (__attribute__((address_space(3))) unsigned int*)(void*)(ldst), 16, 0, 0)

// Workspace:
//   ph  : [CB_N/16][4][64][8] f16   2 MB  (ncb*256 hi, B-frag packed)
//   pl  : same                      2 MB
//   rph : [32*8][64][8] f16         0.25 MB (rp*64 hi, B-frag packed)
//   rpl : same                      0.25 MB

// ---------------------------------------------------------------------------
// Kernel 1 (fused packs): blocks [0,512) pack codebook, blocks [512,544)
// pack rp via LDS-staged coalesced loads. (validated r1/r2)
// ---------------------------------------------------------------------------
__global__ __launch_bounds__(256) void pack_all_kernel(
    const float* __restrict__ cb, _Float16* __restrict__ ph,
    _Float16* __restrict__ pl,
    const float* __restrict__ rp, _Float16* __restrict__ rph,
    _Float16* __restrict__ rpl) {
    __shared__ float L[16][129];
    __shared__ float R[32][132];
    const int t = threadIdx.x;
    const int b = blockIdx.x;

    if (b < 512) {
        const int g = b;
        const int c = t >> 4, p = t & 15;
        const float4 v0 = *(const float4*)&cb[(size_t)(g * 16 + c) * E_DIM + p * 8];
        const float4 v1 = *(const float4*)&cb[(size_t)(g * 16 + c) * E_DIM + p * 8 + 4];
        float ss = v0.x * v0.x + v0.y * v0.y + v0.z * v0.z + v0.w * v0.w
                 + v1.x * v1.x + v1.y * v1.y + v1.z * v1.z + v1.w * v1.w;
#pragma unroll
        for (int m = 1; m < 16; m <<= 1) ss += __shfl_xor(ss, m);
        const float inv = 256.0f / fmaxf(sqrtf(ss), 1e-12f);

        L[c][p * 8 + 0] = v0.x * inv; L[c][p * 8 + 1] = v0.y * inv;
        L[c][p * 8 + 2] = v0.z * inv; L[c][p * 8 + 3] = v0.w * inv;
        L[c][p * 8 + 4] = v1.x * inv; L[c][p * 8 + 5] = v1.y * inv;
        L[c][p * 8 + 6] = v1.z * inv; L[c][p * 8 + 7] = v1.w * inv;
        __syncthreads();

        const int kb = t >> 6, lane = t & 63;
        const int quad = (lane >> 4), col = lane & 15;
        f16x8 h, l;
#pragma unroll
        for (int j = 0; j < 8; ++j) {
            const float v = L[col][kb * 32 + quad * 8 + j];
            const _Float16 hv = (_Float16)v;
            h[j] = hv;
            l[j] = (_Float16)(v - (float)hv);
        }
        const size_t off = ((size_t)(g * 4 + kb) * 64 + lane) * 8;
        *(f16x8*)&ph[off] = h;
        *(f16x8*)&pl[off] = l;
    } else {
        const int kb = b - 512;
        const int r = t >> 3, c0 = (t & 7) * 16;
#pragma unroll
        for (int i = 0; i < 4; ++i)
            *(float4*)&R[r][c0 + i * 4] =
                *(const float4*)&rp[(size_t)(kb * 32 + r) * E_DIM + c0 + i * 4];
        __syncthreads();

        const int w = t >> 6, lane = t & 63;
        const int quad = lane >> 4, col = lane & 15;
#pragma unroll
        for (int h2 = 0; h2 < 2; ++h2) {
            const int nt = w * 2 + h2;
            f16x8 hh, ll;
#pragma unroll
            for (int j = 0; j < 8; ++j) {
                const float v = R[quad * 8 + j][nt * 16 + col] * 64.0f;
                const _Float16 hv = (_Float16)v;
                hh[j] = hv;
                ll[j] = (_Float16)(v - (float)hv);
            }
            const size_t off = ((size_t)((kb * 8 + nt) * 64) + lane) * 8;
            *(f16x8*)&rph[off] = hh;
            *(f16x8*)&rpl[off] = ll;
        }
    }
}

// ---------------------------------------------------------------------------
// Kernel 2: FUSED proj + scores + argmax. Qtile=128, 512 threads, 8 waves,
// grid 256 (1 block/CU), __launch_bounds__(512,2) -> VGPR cap 256 (no spill).
// Phase 1 (r2-validated): barrier-free direct-from-global proj; wave w:
//   wq1=w>>2 (query 64-half), wn=w&3 (e-tile pair). P[128][132] f32 -> LDS.
// Phase 2 (NEW): wave w owns m-tile w (16 queries), ALL waves scan ALL 8192
//   codes. Codebook frags staged L2->LDS via global_load_lds (zero-VGPR DMA)
//   in 64-code double-buffered chunks aliasing the dead P buffer.
//   Per-CU codebook pull: 4 MB total (~17 B/cy) vs r1's ~69 B/cy demand.
//   No cross-wave argmax merge needed (each wave sees all codes).
// ---------------------------------------------------------------------------
#define PPITCH   132                  // proj buffer row pitch (dwords)
#define P_BYTES  (128 * PPITCH * 4)   // 67,584 B (proven static size in r2)
#define CH_BYTES 32768                // 64 codes: 4 tiles x (hi+lo) x 4KB
#define NCHUNK   128                  // 8192 codes / 64

__global__ __launch_bounds__(512, 2) void fused_kernel(
    const float* __restrict__ x,
    const _Float16* __restrict__ rph, const _Float16* __restrict__ rpl,
    const _Float16* __restrict__ ph, const _Float16* __restrict__ pl,
    int* __restrict__ out) {
    __shared__ __align__(16) char SMEM[P_BYTES];   // P (phase1) | Bst[2] (phase2)

    const int tid  = threadIdx.x;
    const int lane = tid & 63;
    const int w    = tid >> 6;
    const int quad = lane >> 4, col = lane & 15;
    const int qb   = blockIdx.x * 128;

    float* Pf  = (float*)SMEM;
    char*  Bst = SMEM;

    // ======================= Phase 1: projection (LDS-free) =================
    const int wn  = w & 3;      // e-tile pair: nt = wn*2 + h
    const int wq1 = w >> 2;     // query 64-half
    const int qbw = qb + wq1 * 64;

    const float* xr[4];
#pragma unroll
    for (int mt = 0; mt < 4; ++mt)
        xr[mt] = x + (size_t)(qbw + mt * 16 + col) * D_IN + quad * 8;

    f32x4 acc[4][2];
#pragma unroll
    for (int mt = 0; mt < 4; ++mt)
#pragma unroll
        for (int h = 0; h < 2; ++h) acc[mt][h] = (f32x4){0.f, 0.f, 0.f, 0.f};

    float4 pA[4][2];
#pragma unroll
    for (int mt = 0; mt < 4; ++mt) {
        pA[mt][0] = *(const float4*)(xr[mt] + 0);
        pA[mt][1] = *(const float4*)(xr[mt] + 4);
    }
    f16x8 bhc[2], blc[2];
#pragma unroll
    for (int h = 0; h < 2; ++h) {
        const size_t off = ((size_t)(wn * 2 + h) * 64 + lane) * 8;
        bhc[h] = *(const f16x8*)&rph[off];
        blc[h] = *(const f16x8*)&rpl[off];
    }

    for (int kb = 0; kb < 32; ++kb) {
        f16x8 ah1[4], al1[4];
#pragma unroll
        for (int mt = 0; mt < 4; ++mt) {
            const float vv[8] = {pA[mt][0].x, pA[mt][0].y, pA[mt][0].z, pA[mt][0].w,
                                 pA[mt][1].x, pA[mt][1].y, pA[mt][1].z, pA[mt][1].w};
            f16x8 hh, ll;
#pragma unroll
            for (int j = 0; j < 8; ++j) {
                const float v = vv[j] * 512.0f;
                const _Float16 hv = (_Float16)v;
                hh[j] = hv;
                ll[j] = (_Float16)(v - (float)hv);
            }
            ah1[mt] = hh;
            al1[mt] = ll;
        }

        if (kb + 1 < 32) {
#pragma unroll
            for (int mt = 0; mt < 4; ++mt) {
                pA[mt][0] = *(const float4*)(xr[mt] + (kb + 1) * 32);
                pA[mt][1] = *(const float4*)(xr[mt] + (kb + 1) * 32 + 4);
            }
        }

        f16x8 bh1[2] = {bhc[0], bhc[1]};
        f16x8 bl1[2] = {blc[0], blc[1]};
        if (kb + 1 < 32) {
#pragma unroll
            for (int h = 0; h < 2; ++h) {
                const size_t off = ((size_t)((kb + 1) * 8 + wn * 2 + h) * 64 + lane) * 8;
                bhc[h] = *(const f16x8*)&rph[off];
                blc[h] = *(const f16x8*)&rpl[off];
            }
        }

#pragma unroll
        for (int mt = 0; mt < 4; ++mt)
#pragma unroll
            for (int h = 0; h < 2; ++h)
                acc[mt][h] = __builtin_amdgcn_mfma_f32_16x16x32_f16(ah1[mt], bh1[h], acc[mt][h], 0, 0, 0);
#pragma unroll
        for (int mt = 0; mt < 4; ++mt)
#pragma unroll
            for (int h = 0; h < 2; ++h)
                acc[mt][h] = __builtin_amdgcn_mfma_f32_16x16x32_f16(ah1[mt], bl1[h], acc[mt][h], 0, 0, 0);
#pragma unroll
        for (int mt = 0; mt < 4; ++mt)
#pragma unroll
            for (int h = 0; h < 2; ++h)
                acc[mt][h] = __builtin_amdgcn_mfma_f32_16x16x32_f16(al1[mt], bh1[h], acc[mt][h], 0, 0, 0);
    }

    // Write proj*16 (f32) to LDS. C/D: row = mt*16 + quad*4 + r, col(e) = h*16 + col.
#pragma unroll
    for (int mt = 0; mt < 4; ++mt)
#pragma unroll
        for (int h = 0; h < 2; ++h)
#pragma unroll
            for (int r = 0; r < 4; ++r) {
                const int row = wq1 * 64 + mt * 16 + quad * 4 + r;
                const int cc  = wn * 32 + h * 16 + col;
                Pf[row * PPITCH + cc] = acc[mt][h][r] * (1.0f / 2048.0f);
            }
    __syncthreads();

    // ======================= Phase 2: scores + argmax =======================
    // A frags for m-tile w: A[m=col][k=quad*8+j], split hi/lo.
    f16x8 ah[4], al[4];
#pragma unroll
    for (int kb = 0; kb < 4; ++kb) {
        const int base = (w * 16 + col) * PPITCH + kb * 32 + quad * 8;
        const float4 v0 = *(const float4*)&Pf[base];
        const float4 v1 = *(const float4*)&Pf[base + 4];
        const float vv[8] = {v0.x, v0.y, v0.z, v0.w, v1.x, v1.y, v1.z, v1.w};
        f16x8 hh, ll;
#pragma unroll
        for (int j = 0; j < 8; ++j) {
            const _Float16 hv = (_Float16)vv[j];
            hh[j] = hv;
            ll[j] = (_Float16)(vv[j] - (float)hv);
        }
        ah[kb] = hh;
        al[kb] = ll;
    }
    __syncthreads();   // everyone done with P; Bst may now overwrite it

    // Staging: 32 x 1KB DMA per chunk, 4 per wave. idx -> (ti, sel, kb).
    // LDS: off = buf*CH_BYTES + ti*8192 + sel*4096 + kb*1024 (+ lane*16 by HW).
    // Global: (sel? pl : ph) + ((g*4+kb)*1024 + lane*16), g = chunk*4 + ti.
    const char* const sb[2] = {(const char*)ph, (const char*)pl};
    int sti[4], ssel[4], skb[4];
#pragma unroll
    for (int i = 0; i < 4; ++i) {
        const int idx = w * 4 + i;
        sti[i] = idx >> 3; ssel[i] = (idx >> 2) & 1; skb[i] = idx & 3;
    }

    // prologue: stage chunk 0 into buf 0
#pragma unroll
    for (int i = 0; i < 4; ++i) {
        const char* g = sb[ssel[i]] + (size_t)((0 + sti[i]) * 4 + skb[i]) * 1024 + (size_t)lane * 16;
        char* l = Bst + sti[i] * 8192 + ssel[i] * 4096 + skb[i] * 1024;
        GLL16(g, l);
    }
    __syncthreads();

    float bs[4];
    int   bi[4];
#pragma unroll
    for (int s = 0; s < 4; ++s) { bs[s] = -FLT_MAX; bi[s] = 0; }

    for (int c = 0; c < NCHUNK; ++c) {
        const int cur = c & 1;
        // issue next-chunk DMA early (lands during this chunk's 48 MFMAs)
        if (c + 1 < NCHUNK) {
            const int nxt = cur ^ 1;
#pragma unroll
            for (int i = 0; i < 4; ++i) {
                const char* g = sb[ssel[i]] + (size_t)(((c + 1) * 4 + sti[i]) * 4 + skb[i]) * 1024 + (size_t)lane * 16;
                char* l = Bst + nxt * CH_BYTES + sti[i] * 8192 + ssel[i] * 4096 + skb[i] * 1024;
                GLL16(g, l);
            }
        }

        const char* bb = Bst + cur * CH_BYTES + (size_t)lane * 16;
#pragma unroll
        for (int p = 0; p < 2; ++p) {
            f16x8 bhA[4], blA[4], bhB[4], blB[4];
#pragma unroll
            for (int kb = 0; kb < 4; ++kb) {
                bhA[kb] = *(const f16x8*)(bb + (p * 2 + 0) * 8192 + kb * 1024);
                blA[kb] = *(const f16x8*)(bb + (p * 2 + 0) * 8192 + 4096 + kb * 1024);
                bhB[kb] = *(const f16x8*)(bb + (p * 2 + 1) * 8192 + kb * 1024);
                blB[kb] = *(const f16x8*)(bb + (p * 2 + 1) * 8192 + 4096 + kb * 1024);
            }

            f32x4 sA = (f32x4){0.f, 0.f, 0.f, 0.f};
            f32x4 sB = (f32x4){0.f, 0.f, 0.f, 0.f};

            __builtin_amdgcn_s_setprio(1);
#pragma unroll
            for (int kb = 0; kb < 4; ++kb) {
                sA = __builtin_amdgcn_mfma_f32_16x16x32_f16(ah[kb], bhA[kb], sA, 0, 0, 0);
                sB = __builtin_amdgcn_mfma_f32_16x16x32_f16(ah[kb], bhB[kb], sB, 0, 0, 0);
            }
#pragma unroll
            for (int kb = 0; kb < 4; ++kb) {
                sA = __builtin_amdgcn_mfma_f32_16x16x32_f16(ah[kb], blA[kb], sA, 0, 0, 0);
                sB = __builtin_amdgcn_mfma_f32_16x16x32_f16(ah[kb], blB[kb], sB, 0, 0, 0);
            }
#pragma unroll
            for (int kb = 0; kb < 4; ++kb) {
                sA = __builtin_amdgcn_mfma_f32_16x16x32_f16(al[kb], bhA[kb], sA, 0, 0, 0);
                sB = __builtin_amdgcn_mfma_f32_16x16x32_f16(al[kb], bhB[kb], sB, 0, 0, 0);
            }
            __builtin_amdgcn_s_setprio(0);

            const int codeA = c * 64 + (p * 2 + 0) * 16 + col;
            const int codeB = c * 64 + (p * 2 + 1) * 16 + col;
#pragma unroll
            for (int r = 0; r < 4; ++r) {
                if (sA[r] > bs[r]) { bs[r] = sA[r]; bi[r] = codeA; }  // ascending: > keeps min idx
            }
#pragma unroll
            for (int r = 0; r < 4; ++r) {
                if (sB[r] > bs[r]) { bs[r] = sB[r]; bi[r] = codeB; }
            }
        }

        if (c + 1 < NCHUNK) __syncthreads();
    }

    // Reduce the 16 code-columns per query (lanes differ in low 4 bits).
#pragma unroll
    for (int s = 0; s < 4; ++s) {
#pragma unroll
        for (int m = 1; m < 16; m <<= 1) {
            const float os = __shfl_xor(bs[s], m);
            const int   oi = __shfl_xor(bi[s], m);
            if (os > bs[s] || (os == bs[s] && oi < bi[s])) { bs[s] = os; bi[s] = oi; }
        }
    }

    // Each wave covers all codes for its 16 queries: direct write, no merge.
    if (col == 0) {
#pragma unroll
        for (int r = 0; r < 4; ++r)
            out[qb + w * 16 + quad * 4 + r] = bi[r];
    }
}

// ---------------------------------------------------------------------------
extern "C" void kernel_launch(void* const* d_in, const int* in_sizes, int n_in,
                              void* d_out, int out_size, void* d_ws, size_t ws_size,
                              hipStream_t stream) {
    const float* x  = (const float*)d_in[0];   // [8,4096,1024]
    const float* rp = (const float*)d_in[1];   // [1024,128]
    const float* cb = (const float*)d_in[2];   // [8192,128]
    int* out = (int*)d_out;                    // [8,4096] int32

    _Float16* ph  = (_Float16*)d_ws;                         // 2 MB
    _Float16* pl  = ph  + (size_t)CB_N * E_DIM;              // 2 MB
    _Float16* rph = pl  + (size_t)CB_N * E_DIM;              // 256 KB
    _Float16* rpl = rph + (size_t)D_IN * E_DIM;              // 256 KB

    pack_all_kernel<<<CB_N / 16 + 32, 256, 0, stream>>>(cb, ph, pl, rp, rph, rpl);
    fused_kernel<<<BN / 128, 512, 0, stream>>>(x, rph, rpl, ph, pl, out);
}